// Round 16
// baseline (501.946 us; speedup 1.0000x reference)
//
#include <hip/hip_runtime.h>
#include <math.h>

// Problem constants (b=2, n=4096, k=32, d0=64, d1=16, L=2, rh=16, HEADS=4)
#define BB    2
#define NN    4096
#define KK    32
#define D0    64
#define D1    16
#define D13   48
#define RHD   16
#define NHEAD 4
#define NLAYER 2
#define EPS   1e-6f
#define SCALE 0.18898223650461363f   // 1/sqrt(16 + 12)
#define ETOT  (BB*NN*KK)             // 262144 edges

typedef float  f32x4 __attribute__((ext_vector_type(4)));
typedef short  s16x8 __attribute__((ext_vector_type(8)));
#define MFMA16(a,b,c) __builtin_amdgcn_mfma_f32_16x16x32_bf16(a,b,c,0,0,0)

__device__ __forceinline__ unsigned short f2bf(float x) {
    union { float f; unsigned u; } v; v.f = x;
    unsigned r = v.u + 0x7fffu + ((v.u >> 16) & 1u);
    return (unsigned short)(r >> 16);
}
__device__ __forceinline__ float bf2f(unsigned short h) {
    union { unsigned u; float f; } v; v.u = ((unsigned)h) << 16;
    return v.f;
}
// hi + lo represents x to ~2^-17 rel
__device__ __forceinline__ void split_bf(float x, unsigned short* hi, unsigned short* lo) {
    unsigned short h = f2bf(x);
    *hi = h;
    *lo = f2bf(x - bf2f(h));
}

// 3-product split-precision MFMA: (ah+al)@(bh+bl) minus al@bl term
__device__ __forceinline__ f32x4 mm3(s16x8 ah, s16x8 al, s16x8 bh, s16x8 bl, f32x4 c) {
    c = MFMA16(ah, bh, c);
    c = MFMA16(ah, bl, c);
    c = MFMA16(al, bh, c);
    return c;
}

__device__ __forceinline__ float wred(float v) {
    #pragma unroll
    for (int o = 32; o > 0; o >>= 1) v += __shfl_xor(v, o, 64);
    return v;
}

__device__ __forceinline__ float gelu_t(float x) {
    float x3 = x * x * x;
    return 0.5f * x * (1.0f + tanhf(0.7978845608028654f * (x + 0.044715f * x3)));
}

// ---------------- geometry (once) ----------------
__global__ void geom_kernel(const float* __restrict__ coords,
                            const int* __restrict__ nbr,
                            float* __restrict__ rhat,
                            float* __restrict__ dist) {
    int e = blockIdx.x * blockDim.x + threadIdx.x;
    if (e >= ETOT) return;
    int bn = e / KK;
    int bb = bn / NN;
    int j  = nbr[e];
    const float* cs = coords + (size_t)bn * 3;
    const float* cn = coords + ((size_t)bb * NN + j) * 3;
    float rx = cn[0] - cs[0], ry = cn[1] - cs[1], rz = cn[2] - cs[2];
    float d  = sqrtf(rx * rx + ry * ry + rz * rz);
    float iv = 1.0f / (d + EPS);
    rhat[e * 3 + 0] = rx * iv;
    rhat[e * 3 + 1] = ry * iv;
    rhat[e * 3 + 2] = rz * iv;
    dist[e] = d;
}

// ---------------- prenorm + q projections + per-node hi/lo packs (layer 0) ----
__global__ __launch_bounds__(64) void prenorm_q_kernel(
    const float* __restrict__ f0, const float* __restrict__ f1,
    const float* __restrict__ Wq0, const float* __restrict__ Wq1,
    float* __restrict__ g1,
    float* __restrict__ q0, float* __restrict__ q1,
    unsigned short* __restrict__ g0H, unsigned short* __restrict__ g0L,
    unsigned short* __restrict__ g1mH, unsigned short* __restrict__ g1mL) {
    int node = blockIdx.x;
    int lane = threadIdx.x;
    __shared__ float g0s[D0], g1s[D13];

    float x  = f0[(size_t)node * D0 + lane];
    float mu = wred(x) * (1.0f / D0);
    float dv = x - mu;
    float var = wred(dv * dv) * (1.0f / D0);
    float g0v = dv * rsqrtf(var + EPS);
    split_bf(g0v, &g0H[(size_t)node * D0 + lane], &g0L[(size_t)node * D0 + lane]);
    g0s[lane] = g0v;

    float w = (lane < D13) ? f1[(size_t)node * D13 + lane] : 0.0f;
    float t = wred(w * w);
    float rms = rsqrtf(t * (1.0f / D1) + EPS);
    if (lane < D13) {
        float g1v = w * rms;
        g1[(size_t)node * D13 + lane] = g1v;
        g1s[lane] = g1v;
        int c = lane / 3, m = lane % 3;            // m-major pack for A cols 80..127
        split_bf(g1v, &g1mH[(size_t)node * D13 + m * 16 + c],
                      &g1mL[(size_t)node * D13 + m * 16 + c]);
    }
    __syncthreads();

    float acc = 0.0f;
    #pragma unroll
    for (int c = 0; c < D0; c++) acc += g0s[c] * Wq0[c * D0 + lane];
    q0[(size_t)node * D0 + lane] = acc;
    if (lane < D13) {
        int e = lane / 3, m = lane % 3;
        float a1 = 0.0f;
        #pragma unroll
        for (int c = 0; c < D1; c++) a1 += g1s[c * 3 + m] * Wq1[c * D1 + e];
        q1[(size_t)node * D13 + lane] = a1;
    }
}

// ---------------- per-edge precompute: dot1 + radial hidden (hi/lo) ----------------
__global__ __launch_bounds__(256) void edge_prep_kernel(
    const int* __restrict__ nbr,
    const float* __restrict__ rhatb, const float* __restrict__ distb,
    const float* __restrict__ g1b,
    const float* __restrict__ Rw1, const float* __restrict__ Rb1,
    unsigned short* __restrict__ d1H, unsigned short* __restrict__ d1L,
    unsigned short* __restrict__ rhHg, unsigned short* __restrict__ rhLg) {
    int t = blockIdx.x * 256 + threadIdx.x;     // t = e*16 + c
    int e = t >> 4, c = t & 15;
    int bn = e >> 5;            // e / KK
    int bb = bn >> 12;          // / NN
    int nj = nbr[e];
    const float* g1 = g1b + ((size_t)bb * NN + nj) * D13 + c * 3;
    float d1 = g1[0] * rhatb[e * 3] + g1[1] * rhatb[e * 3 + 1] + g1[2] * rhatb[e * 3 + 2];
    split_bf(d1, &d1H[t], &d1L[t]);
    float rh = gelu_t(distb[e] * Rw1[c] + Rb1[c]);
    split_bf(rh, &rhHg[t], &rhLg[t]);
}

// ---------------- weight pack values ----------------
// GEMM1 B (n in [0,128): [k0|v0], k in [0,96)): rows 0:64 h0, 64:80 dot1, 80:96 zero
__device__ __forceinline__ float B1val(int n, int k,
    const float* Wk00, const float* Wk10, const float* Wv00, const float* Wv10) {
    int nn = n & 63;
    const float* W0 = (n < 64) ? Wk00 : Wv00;
    const float* W1 = (n < 64) ? Wk10 : Wv10;
    if (k < 64) return W0[k * D0 + nn];
    if (k < 80) return W1[(k - 64) * D0 + nn];
    return 0.0f;
}
// GEMM2 B (n in [0,128): [sk|sv|hk(m)|hv(m)], k in [0,128)):
// k rows: 0:64 h0, 64:80 dot1, 80:128 h1 (m-major: k=80+m*16+c)
__device__ __forceinline__ float B2val(int n, int k,
    const float* Wk01, const float* Wk11, const float* Wk11r,
    const float* Wv01, const float* Wv11, const float* Wv11r) {
    if (n < 16) {
        if (k < 64) return Wk01[k * D1 + n];
        if (k < 80) return Wk11r[(k - 64) * D1 + n];
        return 0.0f;
    }
    if (n < 32) {
        int e = n - 16;
        if (k < 64) return Wv01[k * D1 + e];
        if (k < 80) return Wv11r[(k - 64) * D1 + e];
        return 0.0f;
    }
    if (n < 80) {
        int m = (n - 32) >> 4, e = (n - 32) & 15;
        if (k >= 80) { int mm = (k - 80) >> 4, c = (k - 80) & 15; if (mm == m) return Wk11[c * D1 + e]; }
        return 0.0f;
    }
    { int m = (n - 80) >> 4, e = (n - 80) & 15;
      if (k >= 80) { int mm = (k - 80) >> 4, c = (k - 80) & 15; if (mm == m) return Wv11[c * D1 + e]; }
      return 0.0f; }
}

// BOTH layers packed in one dispatch (weights are activation-independent).
// pack layout per layer: P[((ks*NT + nt)*64 + lane)*8 + t]
__global__ void prep_kernel(
    const float* __restrict__ Wk00, const float* __restrict__ Wk10,
    const float* __restrict__ Wk01, const float* __restrict__ Wk11,
    const float* __restrict__ Wk11r,
    const float* __restrict__ Wv00, const float* __restrict__ Wv10,
    const float* __restrict__ Wv01, const float* __restrict__ Wv11,
    const float* __restrict__ Wv11r,
    const float* __restrict__ Rw20, const float* __restrict__ Rw21,
    unsigned short* __restrict__ B1H, unsigned short* __restrict__ B1L,
    unsigned short* __restrict__ B2H, unsigned short* __restrict__ B2L,
    unsigned short* __restrict__ R0H, unsigned short* __restrict__ R0L,
    unsigned short* __restrict__ R1H, unsigned short* __restrict__ R1L) {
    int gid = blockIdx.x * 256 + threadIdx.x;
    if (gid >= 2 * 3904) return;
    int l  = (gid >= 3904) ? 1 : 0;
    int id = gid - l * 3904;
    const float* Wk00l = Wk00 + l * D0 * D0;
    const float* Wk10l = Wk10 + l * D1 * D0;
    const float* Wk01l = Wk01 + l * D0 * D1;
    const float* Wk11l = Wk11 + l * D1 * D1;
    const float* Wk11rl= Wk11r+ l * D1 * D1;
    const float* Wv00l = Wv00 + l * D0 * D0;
    const float* Wv10l = Wv10 + l * D1 * D0;
    const float* Wv01l = Wv01 + l * D0 * D1;
    const float* Wv11l = Wv11 + l * D1 * D1;
    const float* Wv11rl= Wv11r+ l * D1 * D1;
    const float* Rw20l = Rw20 + l * RHD * D0;
    const float* Rw21l = Rw21 + l * RHD * D1;
    unsigned short* B1Hl = B1H + l * 1536 * 8;
    unsigned short* B1Ll = B1L + l * 1536 * 8;
    unsigned short* B2Hl = B2H + l * 2048 * 8;
    unsigned short* B2Ll = B2L + l * 2048 * 8;
    unsigned short* R0Hl = R0H + l * 256 * 8;
    unsigned short* R0Ll = R0L + l * 256 * 8;
    unsigned short* R1Hl = R1H + l * 64 * 8;
    unsigned short* R1Ll = R1L + l * 64 * 8;

    if (id < 1536) {                       // B1: KS=3, NT=8
        int ks = id >> 9, rem = id & 511, nt = rem >> 6, lane = rem & 63;
        int li = lane & 15, quad = lane >> 4;
        #pragma unroll
        for (int t = 0; t < 8; t++) {
            float v = B1val(nt * 16 + li, ks * 32 + quad * 8 + t, Wk00l, Wk10l, Wv00l, Wv10l);
            split_bf(v, &B1Hl[id * 8 + t], &B1Ll[id * 8 + t]);
        }
    } else if (id < 3584) {                // B2: KS=4, NT=8
        int id2 = id - 1536;
        int ks = id2 >> 9, rem = id2 & 511, nt = rem >> 6, lane = rem & 63;
        int li = lane & 15, quad = lane >> 4;
        #pragma unroll
        for (int t = 0; t < 8; t++) {
            float v = B2val(nt * 16 + li, ks * 32 + quad * 8 + t,
                            Wk01l, Wk11l, Wk11rl, Wv01l, Wv11l, Wv11rl);
            split_bf(v, &B2Hl[id2 * 8 + t], &B2Ll[id2 * 8 + t]);
        }
    } else if (id < 3840) {                // R0: KS=1, NT=4 (K=32 padded, real K=16)
        int id2 = id - 3584;
        int nt = id2 >> 6, lane = id2 & 63;
        int li = lane & 15, quad = lane >> 4;
        #pragma unroll
        for (int t = 0; t < 8; t++) {
            int k = quad * 8 + t;
            float v = (k < 16) ? Rw20l[k * D0 + nt * 16 + li] : 0.0f;
            split_bf(v, &R0Hl[id2 * 8 + t], &R0Ll[id2 * 8 + t]);
        }
    } else {                               // R1: KS=1, NT=1
        int id2 = id - 3840;
        int li = id2 & 15, quad = id2 >> 4;
        #pragma unroll
        for (int t = 0; t < 8; t++) {
            int k = quad * 8 + t;
            float v = (k < 16) ? Rw21l[k * D1 + li] : 0.0f;
            split_bf(v, &R1Hl[id2 * 8 + t], &R1Ll[id2 * 8 + t]);
        }
    }
}

// ---------------- fused attention: 2 INDEPENDENT waves per 128-thread block ----
// R16: R15 per-wave structure unchanged; two independent 64-edge waves packed
// per block to test the blocks/CU-residency-cap hypothesis (R14 falsified the
// LDS-per-block theory; this doubles waves/CU iff resident blocks are capped).
// v0s/v1s stored bf16 to fit 2x per-wave LDS (~39 KB total).
// Barriers at every cross-lane LDS handoff (R7 race lesson).
// NOTE: no occupancy floor (R2: __launch_bounds__(...,4) caused VGPR=64 + GB-scale spills)
__global__ __launch_bounds__(128) void attn_fused_kernel(
    const int* __restrict__ nbr_idx,
    const float* __restrict__ rhatg,
    const float* __restrict__ q0g, const float* __restrict__ q1g,
    const unsigned short* __restrict__ g0H, const unsigned short* __restrict__ g0L,
    const unsigned short* __restrict__ g1mH, const unsigned short* __restrict__ g1mL,
    const unsigned short* __restrict__ d1H, const unsigned short* __restrict__ d1L,
    const unsigned short* __restrict__ rhHg, const unsigned short* __restrict__ rhLg,
    const unsigned short* __restrict__ B1H, const unsigned short* __restrict__ B1L,
    const unsigned short* __restrict__ B2H, const unsigned short* __restrict__ B2L,
    const unsigned short* __restrict__ R0H, const unsigned short* __restrict__ R0L,
    const unsigned short* __restrict__ R1H, const unsigned short* __restrict__ R1L,
    const float* __restrict__ Wo0, const float* __restrict__ Wo1,
    float* __restrict__ f0b, float* __restrict__ f1b) {

    int w     = threadIdx.x >> 6;          // wave id (independent tile)
    int lane  = threadIdx.x & 63;
    int B0    = blockIdx.x * 128 + w * 64; // this wave's first edge
    int node0 = blockIdx.x * 4 + w * 2;    // this wave's first node
    int bb    = node0 >> 12;               // / NN
    int li    = lane & 15, quad = lane >> 4;
    int koff  = quad * 8;

    __shared__ float rhts[2][192];
    __shared__ float lgs0[2][64][4];
    __shared__ float lgs1[2][64][4];
    __shared__ unsigned short v0h[2][64][72];   // v0*r0 bf16 (row 144B)
    __shared__ unsigned short v1h[2][64][52];   // v1 bf16
    __shared__ float o0s[2][2][D0];
    __shared__ float o1s[2][2][D13];

    rhts[w][lane]       = rhatg[(size_t)B0 * 3 + lane];
    rhts[w][lane + 64]  = rhatg[(size_t)B0 * 3 + lane + 64];
    rhts[w][lane + 128] = rhatg[(size_t)B0 * 3 + lane + 128];
    __syncthreads();   // (1) rhts handoff

    size_t em[4], nm[4];
    #pragma unroll
    for (int mt = 0; mt < 4; mt++) {
        em[mt] = (size_t)B0 + mt * 16 + li;
        nm[mt] = (size_t)bb * NN + nbr_idx[em[mt]];
    }

    // A-fragment pointers per ks (cols: 0-63 g0, 64-79 dot1, 80-127 g1 m-major)
    #define APTRS(ks, nb, ee, PH, PL)                                              \
        const unsigned short *PH, *PL;                                             \
        if (ks < 2) {                                                              \
            PH = g0H + (nb) * 64 + ks * 32 + koff;                                 \
            PL = g0L + (nb) * 64 + ks * 32 + koff;                                 \
        } else if (ks == 2) {                                                      \
            PH = (quad < 2) ? d1H + (ee) * 16 + quad * 8                           \
                            : g1mH + (nb) * 48 + (quad - 2) * 8;                   \
            PL = (quad < 2) ? d1L + (ee) * 16 + quad * 8                           \
                            : g1mL + (nb) * 48 + (quad - 2) * 8;                   \
        } else {                                                                   \
            PH = (quad < 2) ? g1mH + (nb) * 48 + 16 + quad * 8                     \
                            : g1mH + (nb) * 48 + 32 + (quad - 2) * 8;              \
            PL = (quad < 2) ? g1mL + (nb) * 48 + 16 + quad * 8                     \
                            : g1mL + (nb) * 48 + 32 + (quad - 2) * 8;              \
        }

    f32x4 acc[4][8];

    // ---- GEMM1: A[64x96] @ B1[96x128] -> k0|v0 ----
    #pragma unroll
    for (int i = 0; i < 4; i++)
        #pragma unroll
        for (int j = 0; j < 8; j++) acc[i][j] = (f32x4){0.f, 0.f, 0.f, 0.f};
    #pragma unroll
    for (int ks = 0; ks < 3; ks++) {
        s16x8 ah[4], al[4];
        #pragma unroll
        for (int mt = 0; mt < 4; mt++) {
            APTRS(ks, nm[mt], em[mt], pH, pL)
            ah[mt] = *(const s16x8*)pH;
            al[mt] = *(const s16x8*)pL;
        }
        #pragma unroll
        for (int nt = 0; nt < 8; nt++) {
            s16x8 bh = *(const s16x8*)(B1H + ((ks * 8 + nt) * 64 + lane) * 8);
            s16x8 bl = *(const s16x8*)(B1L + ((ks * 8 + nt) * 64 + lane) * 8);
            #pragma unroll
            for (int mt = 0; mt < 4; mt++)
                acc[mt][nt] = mm3(ah[mt], al[mt], bh, bl, acc[mt][nt]);
        }
    }

    // ---- radial r0 GEMM ----
    {
        f32x4 r0a[4][4];
        #pragma unroll
        for (int i = 0; i < 4; i++)
            #pragma unroll
            for (int j = 0; j < 4; j++) r0a[i][j] = (f32x4){0.f, 0.f, 0.f, 0.f};
        s16x8 zz = (s16x8){0,0,0,0,0,0,0,0};
        s16x8 rah[4], ral[4];
        #pragma unroll
        for (int mt = 0; mt < 4; mt++) {
            rah[mt] = zz; ral[mt] = zz;
            if (quad < 2) {
                rah[mt] = *(const s16x8*)(rhHg + em[mt] * 16 + koff);
                ral[mt] = *(const s16x8*)(rhLg + em[mt] * 16 + koff);
            }
        }
        #pragma unroll
        for (int nt = 0; nt < 4; nt++) {
            s16x8 bh = *(const s16x8*)(R0H + (nt * 64 + lane) * 8);
            s16x8 bl = *(const s16x8*)(R0L + (nt * 64 + lane) * 8);
            #pragma unroll
            for (int mt = 0; mt < 4; mt++)
                r0a[mt][nt] = mm3(rah[mt], ral[mt], bh, bl, r0a[mt][nt]);
        }

        // ---- epilogue1: q0.k0 logits -> lgs0; v0*r0 -> v0h (bf16) ----
        float q0e[2][4];
        #pragma unroll
        for (int nw = 0; nw < 2; nw++)
            #pragma unroll
            for (int nt = 0; nt < 4; nt++)
                q0e[nw][nt] = q0g[(size_t)(node0 + nw) * D0 + nt * 16 + li];
        #pragma unroll
        for (int mt = 0; mt < 4; mt++) {
            int nw = mt >> 1;
            float p0[4][4];
            #pragma unroll
            for (int nt = 0; nt < 4; nt++)
                #pragma unroll
                for (int r = 0; r < 4; r++)
                    p0[nt][r] = q0e[nw][nt] * (acc[mt][nt][r] * r0a[mt][nt][r]);
            #pragma unroll
            for (int off = 1; off < 16; off <<= 1) {
                #pragma unroll
                for (int nt = 0; nt < 4; nt++)
                    #pragma unroll
                    for (int r = 0; r < 4; r++)
                        p0[nt][r] += __shfl_xor(p0[nt][r], off, 16);
            }
            if (li == 0) {
                int jb = mt * 16 + quad * 4;
                #pragma unroll
                for (int r = 0; r < 4; r++)
                    #pragma unroll
                    for (int nt = 0; nt < 4; nt++)
                        lgs0[w][jb + r][nt] = p0[nt][r];
            }
            #pragma unroll
            for (int nt = 0; nt < 4; nt++)
                #pragma unroll
                for (int r = 0; r < 4; r++)
                    v0h[w][mt * 16 + quad * 4 + r][nt * 16 + li] =
                        f2bf(acc[mt][nt + 4][r] * r0a[mt][nt][r]);
        }
    }

    // ---- radial r1 GEMM (rh fragments reloaded; r0a freed above) ----
    f32x4 r1a[4];
    {
        s16x8 zz = (s16x8){0,0,0,0,0,0,0,0};
        s16x8 bh = *(const s16x8*)(R1H + lane * 8);
        s16x8 bl = *(const s16x8*)(R1L + lane * 8);
        #pragma unroll
        for (int mt = 0; mt < 4; mt++) {
            s16x8 rah = zz, ral = zz;
            if (quad < 2) {
                rah = *(const s16x8*)(rhHg + em[mt] * 16 + koff);
                ral = *(const s16x8*)(rhLg + em[mt] * 16 + koff);
            }
            r1a[mt] = (f32x4){0.f, 0.f, 0.f, 0.f};
            r1a[mt] = mm3(rah, ral, bh, bl, r1a[mt]);
        }
    }

    // ---- GEMM2: A[64x128] @ B2[128x128] -> sk|sv|hk|hv ----
    #pragma unroll
    for (int i = 0; i < 4; i++)
        #pragma unroll
        for (int j = 0; j < 8; j++) acc[i][j] = (f32x4){0.f, 0.f, 0.f, 0.f};
    #pragma unroll
    for (int ks = 0; ks < 4; ks++) {
        s16x8 ah[4], al[4];
        #pragma unroll
        for (int mt = 0; mt < 4; mt++) {
            APTRS(ks, nm[mt], em[mt], pH, pL)
            ah[mt] = *(const s16x8*)pH;
            al[mt] = *(const s16x8*)pL;
        }
        #pragma unroll
        for (int nt = 0; nt < 8; nt++) {
            s16x8 bh = *(const s16x8*)(B2H + ((ks * 8 + nt) * 64 + lane) * 8);
            s16x8 bl = *(const s16x8*)(B2L + ((ks * 8 + nt) * 64 + lane) * 8);
            #pragma unroll
            for (int mt = 0; mt < 4; mt++)
                acc[mt][nt] = mm3(ah[mt], al[mt], bh, bl, acc[mt][nt]);
        }
    }

    // ---- epilogue2: k1/v1 assembly; v1 -> LDS (bf16); q1.k1 -> lgs1 ----
    {
        float q1v[2][3];
        #pragma unroll
        for (int nw = 0; nw < 2; nw++)
            #pragma unroll
            for (int m = 0; m < 3; m++)
                q1v[nw][m] = q1g[(size_t)(node0 + nw) * D13 + li * 3 + m];
        #pragma unroll
        for (int mt = 0; mt < 4; mt++) {
            int nw = mt >> 1;
            #pragma unroll
            for (int r = 0; r < 4; r++) {
                int j = mt * 16 + quad * 4 + r;
                float r1  = r1a[mt][r];
                float rh0 = rhts[w][j * 3], rh1 = rhts[w][j * 3 + 1], rh2 = rhts[w][j * 3 + 2];
                float sk = acc[mt][0][r], sv = acc[mt][1][r];
                float k1a = (sk * rh0 + acc[mt][2][r]) * r1;
                float k1b = (sk * rh1 + acc[mt][3][r]) * r1;
                float k1c = (sk * rh2 + acc[mt][4][r]) * r1;
                v1h[w][j][li * 3 + 0] = f2bf((sv * rh0 + acc[mt][5][r]) * r1);
                v1h[w][j][li * 3 + 1] = f2bf((sv * rh1 + acc[mt][6][r]) * r1);
                v1h[w][j][li * 3 + 2] = f2bf((sv * rh2 + acc[mt][7][r]) * r1);
                float lc = q1v[nw][0] * k1a + q1v[nw][1] * k1b + q1v[nw][2] * k1c;
                lc += __shfl_xor(lc, 1, 4);
                lc += __shfl_xor(lc, 2, 4);
                if ((li & 3) == 0) lgs1[w][j][li >> 2] = lc;
            }
        }
    }
    __syncthreads();   // (2) lgs0/lgs1/v0h/v1h handoff

    // ---- softmax: all 64 lanes, j = lane; width-32 groups = per-node ----
    {
        float4 a4 = *(const float4*)&lgs0[w][lane][0];
        float4 b4 = *(const float4*)&lgs1[w][lane][0];
        float4 l4;
        l4.x = (a4.x + b4.x) * SCALE; l4.y = (a4.y + b4.y) * SCALE;
        l4.z = (a4.z + b4.z) * SCALE; l4.w = (a4.w + b4.w) * SCALE;
        float4 mx = l4;
        #pragma unroll
        for (int off = 1; off < 32; off <<= 1) {
            mx.x = fmaxf(mx.x, __shfl_xor(mx.x, off, 32));
            mx.y = fmaxf(mx.y, __shfl_xor(mx.y, off, 32));
            mx.z = fmaxf(mx.z, __shfl_xor(mx.z, off, 32));
            mx.w = fmaxf(mx.w, __shfl_xor(mx.w, off, 32));
        }
        float4 ex;
        ex.x = expf(l4.x - mx.x); ex.y = expf(l4.y - mx.y);
        ex.z = expf(l4.z - mx.z); ex.w = expf(l4.w - mx.w);
        float4 s = ex;
        #pragma unroll
        for (int off = 1; off < 32; off <<= 1) {
            s.x += __shfl_xor(s.x, off, 32);
            s.y += __shfl_xor(s.y, off, 32);
            s.z += __shfl_xor(s.z, off, 32);
            s.w += __shfl_xor(s.w, off, 32);
        }
        ex.x /= s.x; ex.y /= s.y; ex.z /= s.z; ex.w /= s.w;
        *(float4*)&lgs0[w][lane][0] = ex;
    }
    __syncthreads();   // (3) softmax weights handoff

    // ---- weighted sums from LDS ----
    {
        int h0 = lane >> 4;
        #pragma unroll
        for (int nw = 0; nw < 2; nw++) {
            float p = 0.0f;
            #pragma unroll
            for (int jn = 0; jn < KK; jn++)
                p += lgs0[w][nw * 32 + jn][h0] * bf2f(v0h[w][nw * 32 + jn][lane]);
            o0s[w][nw][lane] = p;
        }
    }
    if (lane < D13) {
        int h1 = (lane / 3) >> 2;
        #pragma unroll
        for (int nw = 0; nw < 2; nw++) {
            float p = 0.0f;
            #pragma unroll
            for (int jn = 0; jn < KK; jn++)
                p += lgs0[w][nw * 32 + jn][h1] * bf2f(v1h[w][nw * 32 + jn][lane]);
            o1s[w][nw][lane] = p;
        }
    }
    __syncthreads();   // (4) o0s/o1s handoff

    // ---- output projections + residual (both nodes) ----
    #pragma unroll
    for (int nw = 0; nw < 2; nw++) {
        float a0 = 0.0f;
        #pragma unroll
        for (int e = 0; e < D0; e++) a0 += o0s[w][nw][e] * Wo0[e * D0 + lane];
        f0b[(size_t)(node0 + nw) * D0 + lane] += a0;
    }
    if (lane < D13) {
        int f = lane / 3, m = lane % 3;
        #pragma unroll
        for (int nw = 0; nw < 2; nw++) {
            float a1 = 0.0f;
            #pragma unroll
            for (int c = 0; c < D1; c++) a1 += o1s[w][nw][c * 3 + m] * Wo1[c * D1 + f];
            f1b[(size_t)(node0 + nw) * D13 + lane] += a1;
        }
    }
    #undef APTRS
}

// ---------------- fused FFN + next-layer prenorm/q OR final concat ----------------
// wave-per-node FFN with fused tail:
//   last==0 -> compute next layer's prenorm + q projections + hi/lo packs in-wave
//   last==1 -> write the concat output directly (f0b/f1b not updated)
__global__ __launch_bounds__(256) void ffn_kernel(
    const float* __restrict__ F0w1, const float* __restrict__ F0w2,
    const float* __restrict__ F1w1, const float* __restrict__ F1w2,
    float* __restrict__ f0b, float* __restrict__ f1b,
    int last,
    const float* __restrict__ Wq0n, const float* __restrict__ Wq1n,
    float* __restrict__ g1b, float* __restrict__ q0b, float* __restrict__ q1b,
    unsigned short* __restrict__ g0H, unsigned short* __restrict__ g0L,
    unsigned short* __restrict__ g1mH, unsigned short* __restrict__ g1mL,
    float* __restrict__ out) {
    int w    = threadIdx.x >> 6, lane = threadIdx.x & 63;
    int node = blockIdx.x * 4 + w;

    __shared__ float g0s[4][D0];
    __shared__ float g1s[4][D13];
    __shared__ float ts[4][256];
    __shared__ float us[4][192];   // u1: 64e x 3m

    float f0old = f0b[(size_t)node * D0 + lane];
    float f1old = (lane < D13) ? f1b[(size_t)node * D13 + lane] : 0.0f;

    // ---- prenorm (wave-local, width-64 reductions) ----
    {
        float mu = wred(f0old) * (1.0f / D0);
        float dv = f0old - mu;
        float var = wred(dv * dv) * (1.0f / D0);
        g0s[w][lane] = dv * rsqrtf(var + EPS);

        float t = wred(f1old * f1old);
        float rms = rsqrtf(t * (1.0f / D1) + EPS);
        if (lane < D13) g1s[w][lane] = f1old * rms;
    }
    __syncthreads();

    // ---- hidden layer: lane handles hidden units h = u*64 + lane ----
    #pragma unroll
    for (int u = 0; u < 4; u++) {
        int h = u * 64 + lane;
        float acc = 0.0f;
        #pragma unroll
        for (int c = 0; c < D0; c++) acc += g0s[w][c] * F0w1[c * 256 + h];
        ts[w][h] = gelu_t(acc);
    }
    // ---- u1 = g1 @ F1w1 : 192 outputs over 64 lanes (3 each) ----
    #pragma unroll
    for (int u = 0; u < 3; u++) {
        int t = u * 64 + lane;
        int e = t / 3, m = t % 3;
        float acc = 0.0f;
        #pragma unroll
        for (int c = 0; c < D1; c++) acc += g1s[w][c * 3 + m] * F1w1[c * 64 + e];
        us[w][t] = acc;
    }
    __syncthreads();

    // ---- gate (lane = e) ----
    {
        float a = us[w][lane * 3], b = us[w][lane * 3 + 1], c = us[w][lane * 3 + 2];
        float nrm = sqrtf(a * a + b * b + c * c);
        float gate = 1.0f / (1.0f + expf(-nrm));
        us[w][lane * 3 + 0] = a * gate;
        us[w][lane * 3 + 1] = b * gate;
        us[w][lane * 3 + 2] = c * gate;
    }
    __syncthreads();

    // ---- second layers (all 64 lanes busy) ----
    float f0new;
    {
        float acc = 0.0f;
        #pragma unroll 8
        for (int j = 0; j < 256; j++) acc += ts[w][j] * F0w2[j * D0 + lane];
        f0new = f0old + acc;
    }
    float f1new = f1old;
    if (lane < D13) {
        int f = lane / 3, m = lane % 3;
        float acc = 0.0f;
        #pragma unroll
        for (int e = 0; e < 64; e++) acc += us[w][e * 3 + m] * F1w2[e * D1 + f];
        f1new = f1old + acc;
    }

    if (last) {
        // ---- final concat output ----
        out[(size_t)node * (D0 + D13) + lane] = f0new;
        if (lane < D13) out[(size_t)node * (D0 + D13) + D0 + lane] = f1new;
        return;
    }

    f0b[(size_t)node * D0 + lane] = f0new;
    if (lane < D13) f1b[(size_t)node * D13 + lane] = f1new;

    // ---- next-layer prenorm + q (fused; saves a dispatch + f0b/f1b re-read) ----
    float mu = wred(f0new) * (1.0f / D0);
    float dv = f0new - mu;
    float var = wred(dv * dv) * (1.0f / D0);
    float g0v = dv * rsqrtf(var + EPS);
    split_bf(g0v, &g0H[(size_t)node * D0 + lane], &g0L[(size_t)node * D0 + lane]);
    float w1v = (lane < D13) ? f1new : 0.0f;
    float t2 = wred(w1v * w1v);
    float rms2 = rsqrtf(t2 * (1.0f / D1) + EPS);
    g0s[w][lane] = g0v;
    if (lane < D13) {
        float g1v = w1v * rms2;
        g1b[(size_t)node * D13 + lane] = g1v;
        g1s[w][lane] = g1v;
        int c = lane / 3, m = lane % 3;
        split_bf(g1v, &g1mH[(size_t)node * D13 + m * 16 + c],
                      &g1mL[(size_t)node * D13 + m * 16 + c]);
    }
    __syncthreads();

    {
        float acc = 0.0f;
        #pragma unroll
        for (int c = 0; c < D0; c++) acc += g0s[w][c] * Wq0n[c * D0 + lane];
        q0b[(size_t)node * D0 + lane] = acc;
    }
    if (lane < D13) {
        int e = lane / 3, m = lane % 3;
        float a1 = 0.0f;
        #pragma unroll
        for (int c = 0; c < D1; c++) a1 += g1s[w][c * 3 + m] * Wq1n[c * D1 + e];
        q1b[(size_t)node * D13 + lane] = a1;
    }
}

extern "C" void kernel_launch(void* const* d_in, const int* in_sizes, int n_in,
                              void* d_out, int out_size, void* d_ws, size_t ws_size,
                              hipStream_t stream) {
    const float* f0     = (const float*)d_in[0];
    const float* f1     = (const float*)d_in[1];
    const float* coords = (const float*)d_in[2];
    const int*   nbr    = (const int*)d_in[3];
    const float* Wq0    = (const float*)d_in[4];
    const float* Wq1    = (const float*)d_in[5];
    const float* Wk00   = (const float*)d_in[6];
    const float* Wk10   = (const float*)d_in[7];
    const float* Wk01   = (const float*)d_in[8];
    const float* Wk11   = (const float*)d_in[9];
    const float* Wk11r  = (const float*)d_in[10];
    const float* Wv00   = (const float*)d_in[11];
    const float* Wv10   = (const float*)d_in[12];
    const float* Wv01   = (const float*)d_in[13];
    const float* Wv11   = (const float*)d_in[14];
    const float* Wv11r  = (const float*)d_in[15];
    const float* Rw1    = (const float*)d_in[16];
    const float* Rb1    = (const float*)d_in[17];
    const float* Rw20   = (const float*)d_in[18];
    const float* Rw21   = (const float*)d_in[19];
    const float* Wo0    = (const float*)d_in[20];
    const float* Wo1    = (const float*)d_in[21];
    const float* F0w1   = (const float*)d_in[22];
    const float* F0w2   = (const float*)d_in[23];
    const float* F1w1   = (const float*)d_in[24];
    const float* F1w2   = (const float*)d_in[25];
    float* out = (float*)d_out;

    int nodes = BB * NN;

    // workspace layout (~50 MB)
    float* wf = (float*)d_ws;
    float* f0b   = wf; wf += (size_t)nodes * D0;
    float* f1b   = wf; wf += (size_t)nodes * D13;
    float* g1b   = wf; wf += (size_t)nodes * D13;
    float* q0b   = wf; wf += (size_t)nodes * D0;
    float* q1b   = wf; wf += (size_t)nodes * D13;
    float* rhatb = wf; wf += (size_t)ETOT * 3;
    float* distb = wf; wf += (size_t)ETOT;
    unsigned short* wu = (unsigned short*)wf;
    unsigned short* g0H  = wu; wu += (size_t)nodes * D0;
    unsigned short* g0L  = wu; wu += (size_t)nodes * D0;
    unsigned short* g1mH = wu; wu += (size_t)nodes * D13;
    unsigned short* g1mL = wu; wu += (size_t)nodes * D13;
    unsigned short* d1H  = wu; wu += (size_t)ETOT * 16;
    unsigned short* d1L  = wu; wu += (size_t)ETOT * 16;
    unsigned short* rhH  = wu; wu += (size_t)ETOT * 16;
    unsigned short* rhL  = wu; wu += (size_t)ETOT * 16;
    // per-layer weight packs (2 layers, one prep dispatch)
    unsigned short* B1H = wu; wu += 2 * 1536 * 8;
    unsigned short* B1L = wu; wu += 2 * 1536 * 8;
    unsigned short* B2H = wu; wu += 2 * 2048 * 8;
    unsigned short* B2L = wu; wu += 2 * 2048 * 8;
    unsigned short* R0H = wu; wu += 2 * 256 * 8;
    unsigned short* R0L = wu; wu += 2 * 256 * 8;
    unsigned short* R1H = wu; wu += 2 * 64 * 8;
    unsigned short* R1L = wu; wu += 2 * 64 * 8;

    geom_kernel<<<(ETOT + 255) / 256, 256, 0, stream>>>(coords, nbr, rhatb, distb);
    hipMemcpyAsync(f0b, f0, (size_t)nodes * D0 * sizeof(float),
                   hipMemcpyDeviceToDevice, stream);
    hipMemcpyAsync(f1b, f1, (size_t)nodes * D13 * sizeof(float),
                   hipMemcpyDeviceToDevice, stream);

    // both layers' weight packs in one dispatch
    prep_kernel<<<(2 * 3904 + 255) / 256, 256, 0, stream>>>(
        Wk00, Wk10, Wk01, Wk11, Wk11r, Wv00, Wv10, Wv01, Wv11, Wv11r,
        Rw20, Rw21, B1H, B1L, B2H, B2L, R0H, R0L, R1H, R1L);

    // layer-0 prenorm + q
    prenorm_q_kernel<<<nodes, 64, 0, stream>>>(
        f0b, f1b, Wq0, Wq1, g1b, q0b, q1b, g0H, g0L, g1mH, g1mL);

    for (int l = 0; l < NLAYER; l++) {
        int last = (l == NLAYER - 1);
        int ln   = last ? 0 : (l + 1);     // next-layer q weights (unused when last)
        edge_prep_kernel<<<ETOT * 16 / 256, 256, 0, stream>>>(
            nbr, rhatb, distb, g1b, Rw1 + l * RHD, Rb1 + l * RHD,
            d1H, d1L, rhH, rhL);
        attn_fused_kernel<<<ETOT / 128, 128, 0, stream>>>(
            nbr, rhatb, q0b, q1b,
            g0H, g0L, g1mH, g1mL, d1H, d1L, rhH, rhL,
            B1H + l * 1536 * 8, B1L + l * 1536 * 8,
            B2H + l * 2048 * 8, B2L + l * 2048 * 8,
            R0H + l * 256 * 8,  R0L + l * 256 * 8,
            R1H + l * 64 * 8,   R1L + l * 64 * 8,
            Wo0 + l * D0 * D0, Wo1 + l * D1 * D1,
            f0b, f1b);
        ffn_kernel<<<nodes / 4, 256, 0, stream>>>(
            F0w1 + l * D0 * 256, F0w2 + l * 256 * D0,
            F1w1 + l * D1 * 64, F1w2 + l * 64 * D1,
            f0b, f1b, last,
            Wq0 + ln * D0 * D0, Wq1 + ln * D1 * D1,
            g1b, q0b, q1b, g0H, g0L, g1mH, g1mL, out);
    }
}

// Round 17
// 447.832 us; speedup vs baseline: 1.1208x; 1.1208x over previous
//
#include <hip/hip_runtime.h>
#include <math.h>

// Problem constants (b=2, n=4096, k=32, d0=64, d1=16, L=2, rh=16, HEADS=4)
#define BB    2
#define NN    4096
#define KK    32
#define D0    64
#define D1    16
#define D13   48
#define RHD   16
#define NHEAD 4
#define NLAYER 2
#define EPS   1e-6f
#define SCALE 0.18898223650461363f   // 1/sqrt(16 + 12)
#define ETOT  (BB*NN*KK)             // 262144 edges

typedef float  f32x4 __attribute__((ext_vector_type(4)));
typedef short  s16x8 __attribute__((ext_vector_type(8)));
#define MFMA16(a,b,c) __builtin_amdgcn_mfma_f32_16x16x32_bf16(a,b,c,0,0,0)

__device__ __forceinline__ unsigned short f2bf(float x) {
    union { float f; unsigned u; } v; v.f = x;
    unsigned r = v.u + 0x7fffu + ((v.u >> 16) & 1u);
    return (unsigned short)(r >> 16);
}
__device__ __forceinline__ float bf2f(unsigned short h) {
    union { unsigned u; float f; } v; v.u = ((unsigned)h) << 16;
    return v.f;
}
// hi + lo represents x to ~2^-17 rel
__device__ __forceinline__ void split_bf(float x, unsigned short* hi, unsigned short* lo) {
    unsigned short h = f2bf(x);
    *hi = h;
    *lo = f2bf(x - bf2f(h));
}

// 3-product split-precision MFMA: (ah+al)@(bh+bl) minus al@bl term
__device__ __forceinline__ f32x4 mm3(s16x8 ah, s16x8 al, s16x8 bh, s16x8 bl, f32x4 c) {
    c = MFMA16(ah, bh, c);
    c = MFMA16(ah, bl, c);
    c = MFMA16(al, bh, c);
    return c;
}

__device__ __forceinline__ float wred(float v) {
    #pragma unroll
    for (int o = 32; o > 0; o >>= 1) v += __shfl_xor(v, o, 64);
    return v;
}

__device__ __forceinline__ float gelu_t(float x) {
    float x3 = x * x * x;
    return 0.5f * x * (1.0f + tanhf(0.7978845608028654f * (x + 0.044715f * x3)));
}

// ---------------- geometry (once) ----------------
__global__ void geom_kernel(const float* __restrict__ coords,
                            const int* __restrict__ nbr,
                            float* __restrict__ rhat,
                            float* __restrict__ dist) {
    int e = blockIdx.x * blockDim.x + threadIdx.x;
    if (e >= ETOT) return;
    int bn = e / KK;
    int bb = bn / NN;
    int j  = nbr[e];
    const float* cs = coords + (size_t)bn * 3;
    const float* cn = coords + ((size_t)bb * NN + j) * 3;
    float rx = cn[0] - cs[0], ry = cn[1] - cs[1], rz = cn[2] - cs[2];
    float d  = sqrtf(rx * rx + ry * ry + rz * rz);
    float iv = 1.0f / (d + EPS);
    rhat[e * 3 + 0] = rx * iv;
    rhat[e * 3 + 1] = ry * iv;
    rhat[e * 3 + 2] = rz * iv;
    dist[e] = d;
}

// ---------------- prenorm + q projections + per-node hi/lo packs (layer 0) ----
__global__ __launch_bounds__(64) void prenorm_q_kernel(
    const float* __restrict__ f0, const float* __restrict__ f1,
    const float* __restrict__ Wq0, const float* __restrict__ Wq1,
    float* __restrict__ g1,
    float* __restrict__ q0, float* __restrict__ q1,
    unsigned short* __restrict__ g0H, unsigned short* __restrict__ g0L,
    unsigned short* __restrict__ g1mH, unsigned short* __restrict__ g1mL) {
    int node = blockIdx.x;
    int lane = threadIdx.x;
    __shared__ float g0s[D0], g1s[D13];

    float x  = f0[(size_t)node * D0 + lane];
    float mu = wred(x) * (1.0f / D0);
    float dv = x - mu;
    float var = wred(dv * dv) * (1.0f / D0);
    float g0v = dv * rsqrtf(var + EPS);
    split_bf(g0v, &g0H[(size_t)node * D0 + lane], &g0L[(size_t)node * D0 + lane]);
    g0s[lane] = g0v;

    float w = (lane < D13) ? f1[(size_t)node * D13 + lane] : 0.0f;
    float t = wred(w * w);
    float rms = rsqrtf(t * (1.0f / D1) + EPS);
    if (lane < D13) {
        float g1v = w * rms;
        g1[(size_t)node * D13 + lane] = g1v;
        g1s[lane] = g1v;
        int c = lane / 3, m = lane % 3;            // m-major pack for A cols 80..127
        split_bf(g1v, &g1mH[(size_t)node * D13 + m * 16 + c],
                      &g1mL[(size_t)node * D13 + m * 16 + c]);
    }
    __syncthreads();

    float acc = 0.0f;
    #pragma unroll
    for (int c = 0; c < D0; c++) acc += g0s[c] * Wq0[c * D0 + lane];
    q0[(size_t)node * D0 + lane] = acc;
    if (lane < D13) {
        int e = lane / 3, m = lane % 3;
        float a1 = 0.0f;
        #pragma unroll
        for (int c = 0; c < D1; c++) a1 += g1s[c * 3 + m] * Wq1[c * D1 + e];
        q1[(size_t)node * D13 + lane] = a1;
    }
}

// ---------------- per-edge precompute: dot1 + radial hidden (hi/lo) ----------------
__global__ __launch_bounds__(256) void edge_prep_kernel(
    const int* __restrict__ nbr,
    const float* __restrict__ rhatb, const float* __restrict__ distb,
    const float* __restrict__ g1b,
    const float* __restrict__ Rw1, const float* __restrict__ Rb1,
    unsigned short* __restrict__ d1H, unsigned short* __restrict__ d1L,
    unsigned short* __restrict__ rhHg, unsigned short* __restrict__ rhLg) {
    int t = blockIdx.x * 256 + threadIdx.x;     // t = e*16 + c
    int e = t >> 4, c = t & 15;
    int bn = e >> 5;            // e / KK
    int bb = bn >> 12;          // / NN
    int nj = nbr[e];
    const float* g1 = g1b + ((size_t)bb * NN + nj) * D13 + c * 3;
    float d1 = g1[0] * rhatb[e * 3] + g1[1] * rhatb[e * 3 + 1] + g1[2] * rhatb[e * 3 + 2];
    split_bf(d1, &d1H[t], &d1L[t]);
    float rh = gelu_t(distb[e] * Rw1[c] + Rb1[c]);
    split_bf(rh, &rhHg[t], &rhLg[t]);
}

// ---------------- weight pack values ----------------
// GEMM1 B (n in [0,128): [k0|v0], k in [0,96)): rows 0:64 h0, 64:80 dot1, 80:96 zero
__device__ __forceinline__ float B1val(int n, int k,
    const float* Wk00, const float* Wk10, const float* Wv00, const float* Wv10) {
    int nn = n & 63;
    const float* W0 = (n < 64) ? Wk00 : Wv00;
    const float* W1 = (n < 64) ? Wk10 : Wv10;
    if (k < 64) return W0[k * D0 + nn];
    if (k < 80) return W1[(k - 64) * D0 + nn];
    return 0.0f;
}
// GEMM2 B (n in [0,128): [sk|sv|hk(m)|hv(m)], k in [0,128)):
// k rows: 0:64 h0, 64:80 dot1, 80:128 h1 (m-major: k=80+m*16+c)
__device__ __forceinline__ float B2val(int n, int k,
    const float* Wk01, const float* Wk11, const float* Wk11r,
    const float* Wv01, const float* Wv11, const float* Wv11r) {
    if (n < 16) {
        if (k < 64) return Wk01[k * D1 + n];
        if (k < 80) return Wk11r[(k - 64) * D1 + n];
        return 0.0f;
    }
    if (n < 32) {
        int e = n - 16;
        if (k < 64) return Wv01[k * D1 + e];
        if (k < 80) return Wv11r[(k - 64) * D1 + e];
        return 0.0f;
    }
    if (n < 80) {
        int m = (n - 32) >> 4, e = (n - 32) & 15;
        if (k >= 80) { int mm = (k - 80) >> 4, c = (k - 80) & 15; if (mm == m) return Wk11[c * D1 + e]; }
        return 0.0f;
    }
    { int m = (n - 80) >> 4, e = (n - 80) & 15;
      if (k >= 80) { int mm = (k - 80) >> 4, c = (k - 80) & 15; if (mm == m) return Wv11[c * D1 + e]; }
      return 0.0f; }
}

// BOTH layers packed in one dispatch (weights are activation-independent).
// pack layout per layer: P[((ks*NT + nt)*64 + lane)*8 + t]
__global__ void prep_kernel(
    const float* __restrict__ Wk00, const float* __restrict__ Wk10,
    const float* __restrict__ Wk01, const float* __restrict__ Wk11,
    const float* __restrict__ Wk11r,
    const float* __restrict__ Wv00, const float* __restrict__ Wv10,
    const float* __restrict__ Wv01, const float* __restrict__ Wv11,
    const float* __restrict__ Wv11r,
    const float* __restrict__ Rw20, const float* __restrict__ Rw21,
    unsigned short* __restrict__ B1H, unsigned short* __restrict__ B1L,
    unsigned short* __restrict__ B2H, unsigned short* __restrict__ B2L,
    unsigned short* __restrict__ R0H, unsigned short* __restrict__ R0L,
    unsigned short* __restrict__ R1H, unsigned short* __restrict__ R1L) {
    int gid = blockIdx.x * 256 + threadIdx.x;
    if (gid >= 2 * 3904) return;
    int l  = (gid >= 3904) ? 1 : 0;
    int id = gid - l * 3904;
    const float* Wk00l = Wk00 + l * D0 * D0;
    const float* Wk10l = Wk10 + l * D1 * D0;
    const float* Wk01l = Wk01 + l * D0 * D1;
    const float* Wk11l = Wk11 + l * D1 * D1;
    const float* Wk11rl= Wk11r+ l * D1 * D1;
    const float* Wv00l = Wv00 + l * D0 * D0;
    const float* Wv10l = Wv10 + l * D1 * D0;
    const float* Wv01l = Wv01 + l * D0 * D1;
    const float* Wv11l = Wv11 + l * D1 * D1;
    const float* Wv11rl= Wv11r+ l * D1 * D1;
    const float* Rw20l = Rw20 + l * RHD * D0;
    const float* Rw21l = Rw21 + l * RHD * D1;
    unsigned short* B1Hl = B1H + l * 1536 * 8;
    unsigned short* B1Ll = B1L + l * 1536 * 8;
    unsigned short* B2Hl = B2H + l * 2048 * 8;
    unsigned short* B2Ll = B2L + l * 2048 * 8;
    unsigned short* R0Hl = R0H + l * 256 * 8;
    unsigned short* R0Ll = R0L + l * 256 * 8;
    unsigned short* R1Hl = R1H + l * 64 * 8;
    unsigned short* R1Ll = R1L + l * 64 * 8;

    if (id < 1536) {                       // B1: KS=3, NT=8
        int ks = id >> 9, rem = id & 511, nt = rem >> 6, lane = rem & 63;
        int li = lane & 15, quad = lane >> 4;
        #pragma unroll
        for (int t = 0; t < 8; t++) {
            float v = B1val(nt * 16 + li, ks * 32 + quad * 8 + t, Wk00l, Wk10l, Wv00l, Wv10l);
            split_bf(v, &B1Hl[id * 8 + t], &B1Ll[id * 8 + t]);
        }
    } else if (id < 3584) {                // B2: KS=4, NT=8
        int id2 = id - 1536;
        int ks = id2 >> 9, rem = id2 & 511, nt = rem >> 6, lane = rem & 63;
        int li = lane & 15, quad = lane >> 4;
        #pragma unroll
        for (int t = 0; t < 8; t++) {
            float v = B2val(nt * 16 + li, ks * 32 + quad * 8 + t,
                            Wk01l, Wk11l, Wk11rl, Wv01l, Wv11l, Wv11rl);
            split_bf(v, &B2Hl[id2 * 8 + t], &B2Ll[id2 * 8 + t]);
        }
    } else if (id < 3840) {                // R0: KS=1, NT=4 (K=32 padded, real K=16)
        int id2 = id - 3584;
        int nt = id2 >> 6, lane = id2 & 63;
        int li = lane & 15, quad = lane >> 4;
        #pragma unroll
        for (int t = 0; t < 8; t++) {
            int k = quad * 8 + t;
            float v = (k < 16) ? Rw20l[k * D0 + nt * 16 + li] : 0.0f;
            split_bf(v, &R0Hl[id2 * 8 + t], &R0Ll[id2 * 8 + t]);
        }
    } else {                               // R1: KS=1, NT=1
        int id2 = id - 3840;
        int li = id2 & 15, quad = id2 >> 4;
        #pragma unroll
        for (int t = 0; t < 8; t++) {
            int k = quad * 8 + t;
            float v = (k < 16) ? Rw21l[k * D1 + li] : 0.0f;
            split_bf(v, &R1Hl[id2 * 8 + t], &R1Ll[id2 * 8 + t]);
        }
    }
}

// ---------------- fused attention: 64 edges (2 nodes) per SINGLE-WAVE block ----
// R17 = R15 restored (session best: 111 µs/layer, 450.8 µs total).
// Occupancy is invariant (~11%) across LDS {16..61KB}, VGPR {132..252},
// block {64,128,256} — per-wave-latency-bound; this config is the optimum.
// Barriers at every cross-lane LDS handoff (R7 race lesson).
// NOTE: no occupancy floor (R2: __launch_bounds__(...,4) caused VGPR=64 + GB-scale spills)
__global__ __launch_bounds__(64) void attn_fused_kernel(
    const int* __restrict__ nbr_idx,
    const float* __restrict__ rhatg,
    const float* __restrict__ q0g, const float* __restrict__ q1g,
    const unsigned short* __restrict__ g0H, const unsigned short* __restrict__ g0L,
    const unsigned short* __restrict__ g1mH, const unsigned short* __restrict__ g1mL,
    const unsigned short* __restrict__ d1H, const unsigned short* __restrict__ d1L,
    const unsigned short* __restrict__ rhHg, const unsigned short* __restrict__ rhLg,
    const unsigned short* __restrict__ B1H, const unsigned short* __restrict__ B1L,
    const unsigned short* __restrict__ B2H, const unsigned short* __restrict__ B2L,
    const unsigned short* __restrict__ R0H, const unsigned short* __restrict__ R0L,
    const unsigned short* __restrict__ R1H, const unsigned short* __restrict__ R1L,
    const float* __restrict__ Wo0, const float* __restrict__ Wo1,
    float* __restrict__ f0b, float* __restrict__ f1b) {

    int B0    = blockIdx.x * 64;       // first edge
    int node0 = blockIdx.x * 2;        // first node
    int bb    = node0 >> 12;           // / NN
    int lane  = threadIdx.x;
    int li    = lane & 15, quad = lane >> 4;
    int koff  = quad * 8;

    __shared__ float rhts[192];      // rhat for 64 edges
    __shared__ float lgs0[64][4];    // q0.k0 logits -> softmax weights
    __shared__ float lgs1[64][4];    // q1.k1 logits
    __shared__ float v0s[64][68];    // v0*r0 (stride 68: quad-stride 16 mod 32 -> 2-way only)
    __shared__ float v1s[64][49];    // v1
    __shared__ float o0s[2][D0];
    __shared__ float o1s[2][D13];

    rhts[lane]       = rhatg[(size_t)B0 * 3 + lane];
    rhts[lane + 64]  = rhatg[(size_t)B0 * 3 + lane + 64];
    rhts[lane + 128] = rhatg[(size_t)B0 * 3 + lane + 128];
    __syncthreads();   // (1) rhts handoff

    size_t em[4], nm[4];
    #pragma unroll
    for (int mt = 0; mt < 4; mt++) {
        em[mt] = (size_t)B0 + mt * 16 + li;
        nm[mt] = (size_t)bb * NN + nbr_idx[em[mt]];
    }

    // A-fragment pointers per ks (cols: 0-63 g0, 64-79 dot1, 80-127 g1 m-major)
    #define APTRS(ks, nb, ee, PH, PL)                                              \
        const unsigned short *PH, *PL;                                             \
        if (ks < 2) {                                                              \
            PH = g0H + (nb) * 64 + ks * 32 + koff;                                 \
            PL = g0L + (nb) * 64 + ks * 32 + koff;                                 \
        } else if (ks == 2) {                                                      \
            PH = (quad < 2) ? d1H + (ee) * 16 + quad * 8                           \
                            : g1mH + (nb) * 48 + (quad - 2) * 8;                   \
            PL = (quad < 2) ? d1L + (ee) * 16 + quad * 8                           \
                            : g1mL + (nb) * 48 + (quad - 2) * 8;                   \
        } else {                                                                   \
            PH = (quad < 2) ? g1mH + (nb) * 48 + 16 + quad * 8                     \
                            : g1mH + (nb) * 48 + 32 + (quad - 2) * 8;              \
            PL = (quad < 2) ? g1mL + (nb) * 48 + 16 + quad * 8                     \
                            : g1mL + (nb) * 48 + 32 + (quad - 2) * 8;              \
        }

    f32x4 acc[4][8];

    // ---- GEMM1: A[64x96] @ B1[96x128] -> k0|v0 ----
    #pragma unroll
    for (int i = 0; i < 4; i++)
        #pragma unroll
        for (int j = 0; j < 8; j++) acc[i][j] = (f32x4){0.f, 0.f, 0.f, 0.f};
    #pragma unroll
    for (int ks = 0; ks < 3; ks++) {
        s16x8 ah[4], al[4];
        #pragma unroll
        for (int mt = 0; mt < 4; mt++) {
            APTRS(ks, nm[mt], em[mt], pH, pL)
            ah[mt] = *(const s16x8*)pH;
            al[mt] = *(const s16x8*)pL;
        }
        #pragma unroll
        for (int nt = 0; nt < 8; nt++) {
            s16x8 bh = *(const s16x8*)(B1H + ((ks * 8 + nt) * 64 + lane) * 8);
            s16x8 bl = *(const s16x8*)(B1L + ((ks * 8 + nt) * 64 + lane) * 8);
            #pragma unroll
            for (int mt = 0; mt < 4; mt++)
                acc[mt][nt] = mm3(ah[mt], al[mt], bh, bl, acc[mt][nt]);
        }
    }

    // ---- radial r0 GEMM ----
    {
        f32x4 r0a[4][4];
        #pragma unroll
        for (int i = 0; i < 4; i++)
            #pragma unroll
            for (int j = 0; j < 4; j++) r0a[i][j] = (f32x4){0.f, 0.f, 0.f, 0.f};
        s16x8 zz = (s16x8){0,0,0,0,0,0,0,0};
        s16x8 rah[4], ral[4];
        #pragma unroll
        for (int mt = 0; mt < 4; mt++) {
            rah[mt] = zz; ral[mt] = zz;
            if (quad < 2) {
                rah[mt] = *(const s16x8*)(rhHg + em[mt] * 16 + koff);
                ral[mt] = *(const s16x8*)(rhLg + em[mt] * 16 + koff);
            }
        }
        #pragma unroll
        for (int nt = 0; nt < 4; nt++) {
            s16x8 bh = *(const s16x8*)(R0H + (nt * 64 + lane) * 8);
            s16x8 bl = *(const s16x8*)(R0L + (nt * 64 + lane) * 8);
            #pragma unroll
            for (int mt = 0; mt < 4; mt++)
                r0a[mt][nt] = mm3(rah[mt], ral[mt], bh, bl, r0a[mt][nt]);
        }

        // ---- epilogue1: q0.k0 logits -> lgs0; v0*r0 -> v0s LDS ----
        float q0e[2][4];
        #pragma unroll
        for (int nw = 0; nw < 2; nw++)
            #pragma unroll
            for (int nt = 0; nt < 4; nt++)
                q0e[nw][nt] = q0g[(size_t)(node0 + nw) * D0 + nt * 16 + li];
        #pragma unroll
        for (int mt = 0; mt < 4; mt++) {
            int nw = mt >> 1;
            float p0[4][4];
            #pragma unroll
            for (int nt = 0; nt < 4; nt++)
                #pragma unroll
                for (int r = 0; r < 4; r++)
                    p0[nt][r] = q0e[nw][nt] * (acc[mt][nt][r] * r0a[mt][nt][r]);
            #pragma unroll
            for (int off = 1; off < 16; off <<= 1) {
                #pragma unroll
                for (int nt = 0; nt < 4; nt++)
                    #pragma unroll
                    for (int r = 0; r < 4; r++)
                        p0[nt][r] += __shfl_xor(p0[nt][r], off, 16);
            }
            if (li == 0) {
                int jb = mt * 16 + quad * 4;
                #pragma unroll
                for (int r = 0; r < 4; r++)
                    #pragma unroll
                    for (int nt = 0; nt < 4; nt++)
                        lgs0[jb + r][nt] = p0[nt][r];
            }
            #pragma unroll
            for (int nt = 0; nt < 4; nt++)
                #pragma unroll
                for (int r = 0; r < 4; r++)
                    v0s[mt * 16 + quad * 4 + r][nt * 16 + li] =
                        acc[mt][nt + 4][r] * r0a[mt][nt][r];
        }
    }

    // ---- radial r1 GEMM (rh fragments reloaded; r0a freed above) ----
    f32x4 r1a[4];
    {
        s16x8 zz = (s16x8){0,0,0,0,0,0,0,0};
        s16x8 bh = *(const s16x8*)(R1H + lane * 8);
        s16x8 bl = *(const s16x8*)(R1L + lane * 8);
        #pragma unroll
        for (int mt = 0; mt < 4; mt++) {
            s16x8 rah = zz, ral = zz;
            if (quad < 2) {
                rah = *(const s16x8*)(rhHg + em[mt] * 16 + koff);
                ral = *(const s16x8*)(rhLg + em[mt] * 16 + koff);
            }
            r1a[mt] = (f32x4){0.f, 0.f, 0.f, 0.f};
            r1a[mt] = mm3(rah, ral, bh, bl, r1a[mt]);
        }
    }

    // ---- GEMM2: A[64x128] @ B2[128x128] -> sk|sv|hk|hv ----
    #pragma unroll
    for (int i = 0; i < 4; i++)
        #pragma unroll
        for (int j = 0; j < 8; j++) acc[i][j] = (f32x4){0.f, 0.f, 0.f, 0.f};
    #pragma unroll
    for (int ks = 0; ks < 4; ks++) {
        s16x8 ah[4], al[4];
        #pragma unroll
        for (int mt = 0; mt < 4; mt++) {
            APTRS(ks, nm[mt], em[mt], pH, pL)
            ah[mt] = *(const s16x8*)pH;
            al[mt] = *(const s16x8*)pL;
        }
        #pragma unroll
        for (int nt = 0; nt < 8; nt++) {
            s16x8 bh = *(const s16x8*)(B2H + ((ks * 8 + nt) * 64 + lane) * 8);
            s16x8 bl = *(const s16x8*)(B2L + ((ks * 8 + nt) * 64 + lane) * 8);
            #pragma unroll
            for (int mt = 0; mt < 4; mt++)
                acc[mt][nt] = mm3(ah[mt], al[mt], bh, bl, acc[mt][nt]);
        }
    }

    // ---- epilogue2: k1/v1 assembly; v1 -> LDS; q1.k1 -> lgs1 ----
    {
        float q1v[2][3];
        #pragma unroll
        for (int nw = 0; nw < 2; nw++)
            #pragma unroll
            for (int m = 0; m < 3; m++)
                q1v[nw][m] = q1g[(size_t)(node0 + nw) * D13 + li * 3 + m];
        #pragma unroll
        for (int mt = 0; mt < 4; mt++) {
            int nw = mt >> 1;
            #pragma unroll
            for (int r = 0; r < 4; r++) {
                int j = mt * 16 + quad * 4 + r;
                float r1  = r1a[mt][r];
                float rh0 = rhts[j * 3], rh1 = rhts[j * 3 + 1], rh2 = rhts[j * 3 + 2];
                float sk = acc[mt][0][r], sv = acc[mt][1][r];
                float k1a = (sk * rh0 + acc[mt][2][r]) * r1;
                float k1b = (sk * rh1 + acc[mt][3][r]) * r1;
                float k1c = (sk * rh2 + acc[mt][4][r]) * r1;
                v1s[j][li * 3 + 0] = (sv * rh0 + acc[mt][5][r]) * r1;
                v1s[j][li * 3 + 1] = (sv * rh1 + acc[mt][6][r]) * r1;
                v1s[j][li * 3 + 2] = (sv * rh2 + acc[mt][7][r]) * r1;
                float lc = q1v[nw][0] * k1a + q1v[nw][1] * k1b + q1v[nw][2] * k1c;
                lc += __shfl_xor(lc, 1, 4);
                lc += __shfl_xor(lc, 2, 4);
                if ((li & 3) == 0) lgs1[j][li >> 2] = lc;
            }
        }
    }
    __syncthreads();   // (2) lgs0/lgs1/v0s/v1s handoff

    // ---- softmax: all 64 lanes, j = lane; width-32 groups = per-node ----
    {
        float4 a4 = *(const float4*)&lgs0[lane][0];
        float4 b4 = *(const float4*)&lgs1[lane][0];
        float4 l4;
        l4.x = (a4.x + b4.x) * SCALE; l4.y = (a4.y + b4.y) * SCALE;
        l4.z = (a4.z + b4.z) * SCALE; l4.w = (a4.w + b4.w) * SCALE;
        float4 mx = l4;
        #pragma unroll
        for (int off = 1; off < 32; off <<= 1) {
            mx.x = fmaxf(mx.x, __shfl_xor(mx.x, off, 32));
            mx.y = fmaxf(mx.y, __shfl_xor(mx.y, off, 32));
            mx.z = fmaxf(mx.z, __shfl_xor(mx.z, off, 32));
            mx.w = fmaxf(mx.w, __shfl_xor(mx.w, off, 32));
        }
        float4 ex;
        ex.x = expf(l4.x - mx.x); ex.y = expf(l4.y - mx.y);
        ex.z = expf(l4.z - mx.z); ex.w = expf(l4.w - mx.w);
        float4 s = ex;
        #pragma unroll
        for (int off = 1; off < 32; off <<= 1) {
            s.x += __shfl_xor(s.x, off, 32);
            s.y += __shfl_xor(s.y, off, 32);
            s.z += __shfl_xor(s.z, off, 32);
            s.w += __shfl_xor(s.w, off, 32);
        }
        ex.x /= s.x; ex.y /= s.y; ex.z /= s.z; ex.w /= s.w;
        *(float4*)&lgs0[lane][0] = ex;
    }
    __syncthreads();   // (3) softmax weights handoff

    // ---- weighted sums from LDS ----
    {
        int h0 = lane >> 4;
        #pragma unroll
        for (int nw = 0; nw < 2; nw++) {
            float p = 0.0f;
            #pragma unroll
            for (int jn = 0; jn < KK; jn++)
                p += lgs0[nw * 32 + jn][h0] * v0s[nw * 32 + jn][lane];
            o0s[nw][lane] = p;
        }
    }
    if (lane < D13) {
        int h1 = (lane / 3) >> 2;
        #pragma unroll
        for (int nw = 0; nw < 2; nw++) {
            float p = 0.0f;
            #pragma unroll
            for (int jn = 0; jn < KK; jn++)
                p += lgs0[nw * 32 + jn][h1] * v1s[nw * 32 + jn][lane];
            o1s[nw][lane] = p;
        }
    }
    __syncthreads();   // (4) o0s/o1s handoff

    // ---- output projections + residual (both nodes) ----
    #pragma unroll
    for (int nw = 0; nw < 2; nw++) {
        float a0 = 0.0f;
        #pragma unroll
        for (int e = 0; e < D0; e++) a0 += o0s[nw][e] * Wo0[e * D0 + lane];
        f0b[(size_t)(node0 + nw) * D0 + lane] += a0;
    }
    if (lane < D13) {
        int f = lane / 3, m = lane % 3;
        #pragma unroll
        for (int nw = 0; nw < 2; nw++) {
            float a1 = 0.0f;
            #pragma unroll
            for (int c = 0; c < D1; c++) a1 += o1s[nw][c * 3 + m] * Wo1[c * D1 + f];
            f1b[(size_t)(node0 + nw) * D13 + lane] += a1;
        }
    }
    #undef APTRS
}

// ---------------- fused FFN + next-layer prenorm/q OR final concat ----------------
// wave-per-node FFN with fused tail:
//   last==0 -> compute next layer's prenorm + q projections + hi/lo packs in-wave
//   last==1 -> write the concat output directly (f0b/f1b not updated)
__global__ __launch_bounds__(256) void ffn_kernel(
    const float* __restrict__ F0w1, const float* __restrict__ F0w2,
    const float* __restrict__ F1w1, const float* __restrict__ F1w2,
    float* __restrict__ f0b, float* __restrict__ f1b,
    int last,
    const float* __restrict__ Wq0n, const float* __restrict__ Wq1n,
    float* __restrict__ g1b, float* __restrict__ q0b, float* __restrict__ q1b,
    unsigned short* __restrict__ g0H, unsigned short* __restrict__ g0L,
    unsigned short* __restrict__ g1mH, unsigned short* __restrict__ g1mL,
    float* __restrict__ out) {
    int w    = threadIdx.x >> 6, lane = threadIdx.x & 63;
    int node = blockIdx.x * 4 + w;

    __shared__ float g0s[4][D0];
    __shared__ float g1s[4][D13];
    __shared__ float ts[4][256];
    __shared__ float us[4][192];   // u1: 64e x 3m

    float f0old = f0b[(size_t)node * D0 + lane];
    float f1old = (lane < D13) ? f1b[(size_t)node * D13 + lane] : 0.0f;

    // ---- prenorm (wave-local, width-64 reductions) ----
    {
        float mu = wred(f0old) * (1.0f / D0);
        float dv = f0old - mu;
        float var = wred(dv * dv) * (1.0f / D0);
        g0s[w][lane] = dv * rsqrtf(var + EPS);

        float t = wred(f1old * f1old);
        float rms = rsqrtf(t * (1.0f / D1) + EPS);
        if (lane < D13) g1s[w][lane] = f1old * rms;
    }
    __syncthreads();

    // ---- hidden layer: lane handles hidden units h = u*64 + lane ----
    #pragma unroll
    for (int u = 0; u < 4; u++) {
        int h = u * 64 + lane;
        float acc = 0.0f;
        #pragma unroll
        for (int c = 0; c < D0; c++) acc += g0s[w][c] * F0w1[c * 256 + h];
        ts[w][h] = gelu_t(acc);
    }
    // ---- u1 = g1 @ F1w1 : 192 outputs over 64 lanes (3 each) ----
    #pragma unroll
    for (int u = 0; u < 3; u++) {
        int t = u * 64 + lane;
        int e = t / 3, m = t % 3;
        float acc = 0.0f;
        #pragma unroll
        for (int c = 0; c < D1; c++) acc += g1s[w][c * 3 + m] * F1w1[c * 64 + e];
        us[w][t] = acc;
    }
    __syncthreads();

    // ---- gate (lane = e) ----
    {
        float a = us[w][lane * 3], b = us[w][lane * 3 + 1], c = us[w][lane * 3 + 2];
        float nrm = sqrtf(a * a + b * b + c * c);
        float gate = 1.0f / (1.0f + expf(-nrm));
        us[w][lane * 3 + 0] = a * gate;
        us[w][lane * 3 + 1] = b * gate;
        us[w][lane * 3 + 2] = c * gate;
    }
    __syncthreads();

    // ---- second layers (all 64 lanes busy) ----
    float f0new;
    {
        float acc = 0.0f;
        #pragma unroll 8
        for (int j = 0; j < 256; j++) acc += ts[w][j] * F0w2[j * D0 + lane];
        f0new = f0old + acc;
    }
    float f1new = f1old;
    if (lane < D13) {
        int f = lane / 3, m = lane % 3;
        float acc = 0.0f;
        #pragma unroll
        for (int e = 0; e < 64; e++) acc += us[w][e * 3 + m] * F1w2[e * D1 + f];
        f1new = f1old + acc;
    }

    if (last) {
        // ---- final concat output ----
        out[(size_t)node * (D0 + D13) + lane] = f0new;
        if (lane < D13) out[(size_t)node * (D0 + D13) + D0 + lane] = f1new;
        return;
    }

    f0b[(size_t)node * D0 + lane] = f0new;
    if (lane < D13) f1b[(size_t)node * D13 + lane] = f1new;

    // ---- next-layer prenorm + q (fused; saves a dispatch + f0b/f1b re-read) ----
    float mu = wred(f0new) * (1.0f / D0);
    float dv = f0new - mu;
    float var = wred(dv * dv) * (1.0f / D0);
    float g0v = dv * rsqrtf(var + EPS);
    split_bf(g0v, &g0H[(size_t)node * D0 + lane], &g0L[(size_t)node * D0 + lane]);
    float w1v = (lane < D13) ? f1new : 0.0f;
    float t2 = wred(w1v * w1v);
    float rms2 = rsqrtf(t2 * (1.0f / D1) + EPS);
    g0s[w][lane] = g0v;
    if (lane < D13) {
        float g1v = w1v * rms2;
        g1b[(size_t)node * D13 + lane] = g1v;
        g1s[w][lane] = g1v;
        int c = lane / 3, m = lane % 3;
        split_bf(g1v, &g1mH[(size_t)node * D13 + m * 16 + c],
                      &g1mL[(size_t)node * D13 + m * 16 + c]);
    }
    __syncthreads();

    {
        float acc = 0.0f;
        #pragma unroll
        for (int c = 0; c < D0; c++) acc += g0s[w][c] * Wq0n[c * D0 + lane];
        q0b[(size_t)node * D0 + lane] = acc;
    }
    if (lane < D13) {
        int e = lane / 3, m = lane % 3;
        float a1 = 0.0f;
        #pragma unroll
        for (int c = 0; c < D1; c++) a1 += g1s[w][c * 3 + m] * Wq1n[c * D1 + e];
        q1b[(size_t)node * D13 + lane] = a1;
    }
}

extern "C" void kernel_launch(void* const* d_in, const int* in_sizes, int n_in,
                              void* d_out, int out_size, void* d_ws, size_t ws_size,
                              hipStream_t stream) {
    const float* f0     = (const float*)d_in[0];
    const float* f1     = (const float*)d_in[1];
    const float* coords = (const float*)d_in[2];
    const int*   nbr    = (const int*)d_in[3];
    const float* Wq0    = (const float*)d_in[4];
    const float* Wq1    = (const float*)d_in[5];
    const float* Wk00   = (const float*)d_in[6];
    const float* Wk10   = (const float*)d_in[7];
    const float* Wk01   = (const float*)d_in[8];
    const float* Wk11   = (const float*)d_in[9];
    const float* Wk11r  = (const float*)d_in[10];
    const float* Wv00   = (const float*)d_in[11];
    const float* Wv10   = (const float*)d_in[12];
    const float* Wv01   = (const float*)d_in[13];
    const float* Wv11   = (const float*)d_in[14];
    const float* Wv11r  = (const float*)d_in[15];
    const float* Rw1    = (const float*)d_in[16];
    const float* Rb1    = (const float*)d_in[17];
    const float* Rw20   = (const float*)d_in[18];
    const float* Rw21   = (const float*)d_in[19];
    const float* Wo0    = (const float*)d_in[20];
    const float* Wo1    = (const float*)d_in[21];
    const float* F0w1   = (const float*)d_in[22];
    const float* F0w2   = (const float*)d_in[23];
    const float* F1w1   = (const float*)d_in[24];
    const float* F1w2   = (const float*)d_in[25];
    float* out = (float*)d_out;

    int nodes = BB * NN;

    // workspace layout (~50 MB)
    float* wf = (float*)d_ws;
    float* f0b   = wf; wf += (size_t)nodes * D0;
    float* f1b   = wf; wf += (size_t)nodes * D13;
    float* g1b   = wf; wf += (size_t)nodes * D13;
    float* q0b   = wf; wf += (size_t)nodes * D0;
    float* q1b   = wf; wf += (size_t)nodes * D13;
    float* rhatb = wf; wf += (size_t)ETOT * 3;
    float* distb = wf; wf += (size_t)ETOT;
    unsigned short* wu = (unsigned short*)wf;
    unsigned short* g0H  = wu; wu += (size_t)nodes * D0;
    unsigned short* g0L  = wu; wu += (size_t)nodes * D0;
    unsigned short* g1mH = wu; wu += (size_t)nodes * D13;
    unsigned short* g1mL = wu; wu += (size_t)nodes * D13;
    unsigned short* d1H  = wu; wu += (size_t)ETOT * 16;
    unsigned short* d1L  = wu; wu += (size_t)ETOT * 16;
    unsigned short* rhH  = wu; wu += (size_t)ETOT * 16;
    unsigned short* rhL  = wu; wu += (size_t)ETOT * 16;
    // per-layer weight packs (2 layers, one prep dispatch)
    unsigned short* B1H = wu; wu += 2 * 1536 * 8;
    unsigned short* B1L = wu; wu += 2 * 1536 * 8;
    unsigned short* B2H = wu; wu += 2 * 2048 * 8;
    unsigned short* B2L = wu; wu += 2 * 2048 * 8;
    unsigned short* R0H = wu; wu += 2 * 256 * 8;
    unsigned short* R0L = wu; wu += 2 * 256 * 8;
    unsigned short* R1H = wu; wu += 2 * 64 * 8;
    unsigned short* R1L = wu; wu += 2 * 64 * 8;

    geom_kernel<<<(ETOT + 255) / 256, 256, 0, stream>>>(coords, nbr, rhatb, distb);
    hipMemcpyAsync(f0b, f0, (size_t)nodes * D0 * sizeof(float),
                   hipMemcpyDeviceToDevice, stream);
    hipMemcpyAsync(f1b, f1, (size_t)nodes * D13 * sizeof(float),
                   hipMemcpyDeviceToDevice, stream);

    // both layers' weight packs in one dispatch
    prep_kernel<<<(2 * 3904 + 255) / 256, 256, 0, stream>>>(
        Wk00, Wk10, Wk01, Wk11, Wk11r, Wv00, Wv10, Wv01, Wv11, Wv11r,
        Rw20, Rw21, B1H, B1L, B2H, B2L, R0H, R0L, R1H, R1L);

    // layer-0 prenorm + q
    prenorm_q_kernel<<<nodes, 64, 0, stream>>>(
        f0b, f1b, Wq0, Wq1, g1b, q0b, q1b, g0H, g0L, g1mH, g1mL);

    for (int l = 0; l < NLAYER; l++) {
        int last = (l == NLAYER - 1);
        int ln   = last ? 0 : (l + 1);     // next-layer q weights (unused when last)
        edge_prep_kernel<<<ETOT * 16 / 256, 256, 0, stream>>>(
            nbr, rhatb, distb, g1b, Rw1 + l * RHD, Rb1 + l * RHD,
            d1H, d1L, rhH, rhL);
        attn_fused_kernel<<<ETOT / 64, 64, 0, stream>>>(
            nbr, rhatb, q0b, q1b,
            g0H, g0L, g1mH, g1mL, d1H, d1L, rhH, rhL,
            B1H + l * 1536 * 8, B1L + l * 1536 * 8,
            B2H + l * 2048 * 8, B2L + l * 2048 * 8,
            R0H + l * 256 * 8,  R0L + l * 256 * 8,
            R1H + l * 64 * 8,   R1L + l * 64 * 8,
            Wo0 + l * D0 * D0, Wo1 + l * D1 * D1,
            f0b, f1b);
        ffn_kernel<<<nodes / 4, 256, 0, stream>>>(
            F0w1 + l * D0 * 256, F0w2 + l * 256 * D0,
            F1w1 + l * D1 * 64, F1w2 + l * 64 * D1,
            f0b, f1b, last,
            Wq0 + ln * D0 * D0, Wq1 + ln * D1 * D1,
            g1b, q0b, q1b, g0H, g0L, g1mH, g1mL, out);
    }
}